// Round 4
// baseline (34915.784 us; speedup 1.0000x reference)
//
#include <hip/hip_runtime.h>
#include <hip/hip_cooperative_groups.h>
#include <math.h>

namespace cg = cooperative_groups;

#define ROWS_ 51200  // B*N = 64*800

typedef _Float16 f16_t;
typedef _Float16 half8 __attribute__((ext_vector_type(8)));
typedef float f32x4 __attribute__((ext_vector_type(4)));

struct Params {
  const float* x_seq; const float* t_x; const float* t_y; const float* G;
  const float* Wraw[8]; const float* bia[8];   // idx = dec*4 + layer*2 + cand
  const float* mW1; const float* mb1; const float* mW2; const float* mb2;
  const float* mem; const float* Wa; const float* fc; const float* projW; const float* projb;
  float* dout;
  float* A1; float* Zg; float* U; float* h0; float* h1;
  float* txe; float* tye; float* hidb; float* partial;
  f16_t* A1h; f16_t* A2h;
  f16_t* wh[8]; f16_t* wl[8];
};

__device__ __forceinline__ float sigm(float x) { return 1.0f / (1.0f + expf(-x)); }

// ================= prologue device funcs =================

__device__ void d_zero(const Params& p) {
  int nt = gridDim.x * blockDim.x, id = blockIdx.x * blockDim.x + threadIdx.x;
  float4 z = {0.f, 0.f, 0.f, 0.f};
  for (int i = id; i < ROWS_ * 16; i += nt) { ((float4*)p.h0)[i] = z; ((float4*)p.h1)[i] = z; }
}

__device__ void d_transp(const Params& p) {
  int nt = gridDim.x * blockDim.x, id = blockIdx.x * blockDim.x + threadIdx.x;
  for (int i = id; i < 640000; i += nt) {
    int m = i / 800, n = i - m * 800;
    float v = p.G[n * 800 + m];
    p.A1[i] = v;
    p.A1h[i] = (f16_t)v;
  }
}

__device__ void d_wsplit(const float* __restrict__ W, f16_t* Wth, f16_t* Wtl, int P, int NC, int Kp) {
  int nt = gridDim.x * blockDim.x, id = blockIdx.x * blockDim.x + threadIdx.x;
  for (int idx = id; idx < Kp * NC; idx += nt) {
    int i = idx / NC, c = idx - i * NC;
    float v = 0.f;
    if (i < 3 * P) {
      int k = i / P, pp = i - k * P;
      if (k == 0)
        v = W[(size_t)pp * NC + c] + 0.05f * (W[(size_t)(P + pp) * NC + c] + W[(size_t)(2 * P + pp) * NC + c]);
      else
        v = 0.95f * W[(size_t)i * NC + c];
    }
    f16_t h = (f16_t)v;
    Wth[(size_t)c * Kp + i] = h;
    Wtl[(size_t)c * Kp + i] = (f16_t)((v - (float)h) * 2048.0f);
  }
}

__device__ void d_mlp_hid(const Params& p, const float* __restrict__ tin, float* hid) {
  int nt = gridDim.x * blockDim.x, id = blockIdx.x * blockDim.x + threadIdx.x;
  for (int idx = id; idx < 7680; idx += nt) {
    int r = idx / 10, j = idx - r * 10;
    float a = p.mb1[j];
    for (int k = 0; k < 60; ++k) a += tin[(size_t)r * 60 + k] * p.mW1[k * 10 + j];
    hid[idx] = a;
  }
}

__device__ void d_mlp_out(const Params& p, const float* __restrict__ hid, float* emb) {
  int nt = gridDim.x * blockDim.x, id = blockIdx.x * blockDim.x + threadIdx.x;
  for (int idx = id; idx < 768 * 1600; idx += nt) {
    int r = idx / 1600, o = idx - r * 1600;
    float a = p.mb2[o];
#pragma unroll
    for (int k = 0; k < 10; ++k) a += hid[r * 10 + k] * p.mW2[k * 1600 + o];
    emb[idx] = a;
  }
}

// T2 = 2*A1@A1 - I, output directly as f16
__device__ void d_t2(const Params& p, char* sm) {
  float* As = (float*)sm;        // [16][68]
  float* Bs = As + 16 * 68;      // [16][68]
  int tid = threadIdx.x, tx = tid & 15, ty = tid >> 4;
  const float* A = p.A1;
  for (int tile = blockIdx.x; tile < 169; tile += gridDim.x) {
    int bx = tile % 13, by = tile / 13;
    int rowBase = by * 64, colBase = bx * 64;
    float acc[4][4] = {};
    for (int k0 = 0; k0 < 800; k0 += 16) {
      __syncthreads();
      for (int e = tid; e < 1024; e += 256) {
        int r = e >> 4, c = e & 15;
        int gr = rowBase + r;
        As[c * 68 + r] = (gr < 800) ? A[gr * 800 + k0 + c] : 0.f;
      }
      for (int e = tid; e < 1024; e += 256) {
        int r = e >> 6, c = e & 63;
        int gc = colBase + c;
        Bs[r * 68 + c] = (gc < 800) ? A[(k0 + r) * 800 + gc] : 0.f;
      }
      __syncthreads();
#pragma unroll
      for (int kk = 0; kk < 16; ++kk) {
        float4 a4 = *(const float4*)&As[kk * 68 + ty * 4];
        float4 b4 = *(const float4*)&Bs[kk * 68 + tx * 4];
        float av[4] = {a4.x, a4.y, a4.z, a4.w};
        float bv[4] = {b4.x, b4.y, b4.z, b4.w};
#pragma unroll
        for (int i = 0; i < 4; ++i)
#pragma unroll
          for (int j = 0; j < 4; ++j) acc[i][j] += av[i] * bv[j];
      }
    }
#pragma unroll
    for (int i = 0; i < 4; ++i) {
      int m = rowBase + ty * 4 + i;
      if (m >= 800) continue;
#pragma unroll
      for (int j = 0; j < 4; ++j) {
        int n = colBase + tx * 4 + j;
        if (n < 800) p.A2h[m * 800 + n] = (f16_t)(2.f * acc[i][j] - (m == n ? 1.f : 0.f));
      }
    }
  }
}

// ================= source gather =================
// mode: 0 = layer0 enc, 1 = layer0 dec, 2 = layer1 [h0|h1], 3 = Zg rh slot
template <int LAYER>
__device__ __forceinline__ float zread(const Params& p, int mode, int t, int b, int n, int c) {
  const int ldz = LAYER ? 384 : 204;
  const int Pin = LAYER ? 64 : 4;
  size_t rn = (size_t)b * 800 + n;
  if (mode == 3) return p.Zg[rn * ldz + Pin + c];
  if (LAYER) return (c < 64) ? p.h0[rn * 64 + c] : p.h1[rn * 64 + (c - 64)];
  if (c >= 4) return p.h0[rn * 64 + (c - 4)];
  if (c < 2) {
    if (mode == 0) return p.x_seq[((size_t)(b * 12 + t) * 800 + n) * 2 + c];
    return (t == 0) ? 0.f : p.dout[((size_t)(b * 12 + (t - 1)) * 800 + n) * 2 + c];
  }
  const float* e = (mode == 0) ? p.txe : p.tye;
  return e[(size_t)(b * 12 + t) * 1600 + n * 2 + (c - 2)];
}

// pack: write Zg[:, 0:P)
template <int LAYER>
__device__ void d_pack(const Params& p, int mode, int t) {
  const int P = LAYER ? 128 : 68;
  const int ldz = 3 * P;
  int nt = gridDim.x * blockDim.x, id = blockIdx.x * blockDim.x + threadIdx.x;
  int total = ROWS_ * P;
  for (int idx = id; idx < total; idx += nt) {
    int row = idx / P, c = idx - row * P;
    int b = row / 800, n = row - b * 800;
    p.Zg[(size_t)row * ldz + c] = zread<LAYER>(p, mode, t, b, n, c);
  }
}

// ================= graph MFMA (both Chebyshev mats) =================
template <int LAYER>
__device__ void d_graph(const Params& p, char* sm, int mode, int t, int inW, int outOff) {
  const int P = LAYER ? 128 : 68;
  const int ldz = 3 * P;
  f16_t* A1S = (f16_t*)sm;       // 128*40
  f16_t* A2S = A1S + 5120;
  f16_t* ZS = A2S + 5120;        // 64*40
  int tid = threadIdx.x;
  int lane = tid & 63, wid = tid >> 6;
  int waveM = wid >> 1, waveN = wid & 1;
  int lrow = lane & 15, lgrp = lane >> 4;
  int arow = tid >> 1, ahalf = tid & 1;
  int zc = tid & 63, zgrp = tid >> 6;
  int gx = (inW + 63) >> 6;
  int nT = gx * 7 * 64;
  for (int tile = blockIdx.x; tile < nT; tile += gridDim.x) {
    int xb = tile % gx;
    int r2 = tile / gx;
    int yb = r2 % 7;
    int b = r2 / 7;
    int rowBase = yb * 128, colBase = xb * 64;
    bool avalid = rowBase + arow < 800;
    bool zvalid = colBase + zc < inW;
    f32x4 acc1[4][2], acc2[4][2];
#pragma unroll
    for (int mt = 0; mt < 4; ++mt)
#pragma unroll
      for (int q = 0; q < 2; ++q) {
        acc1[mt][q] = (f32x4){0.f, 0.f, 0.f, 0.f};
        acc2[mt][q] = (f32x4){0.f, 0.f, 0.f, 0.f};
      }
    for (int k0 = 0; k0 < 800; k0 += 32) {
      __syncthreads();
      {
        size_t gofs = (size_t)(rowBase + arow) * 800 + k0 + ahalf * 16;
        uint4 zz = {0u, 0u, 0u, 0u};
        uint4 a0 = avalid ? *(const uint4*)(p.A1h + gofs) : zz;
        uint4 a1 = avalid ? *(const uint4*)(p.A1h + gofs + 8) : zz;
        uint4 b0 = avalid ? *(const uint4*)(p.A2h + gofs) : zz;
        uint4 b1 = avalid ? *(const uint4*)(p.A2h + gofs + 8) : zz;
        int s = arow * 40 + ahalf * 16;
        *(uint4*)(A1S + s) = a0;
        *(uint4*)(A1S + s + 8) = a1;
        *(uint4*)(A2S + s) = b0;
        *(uint4*)(A2S + s + 8) = b1;
      }
      {
        half8 vh;
#pragma unroll
        for (int i = 0; i < 8; ++i) {
          int n = k0 + zgrp * 8 + i;
          float zv = zvalid ? zread<LAYER>(p, mode, t, b, n, colBase + zc) : 0.f;
          vh[i] = (f16_t)zv;
        }
        *(half8*)(ZS + zc * 40 + zgrp * 8) = vh;
      }
      __syncthreads();
      half8 fz[2];
#pragma unroll
      for (int q = 0; q < 2; ++q) {
        int c = waveN * 32 + q * 16 + lrow;
        fz[q] = *(const half8*)(ZS + c * 40 + lgrp * 8);
      }
#pragma unroll
      for (int mt = 0; mt < 4; ++mt) {
        int r = waveM * 64 + mt * 16 + lrow;
        half8 fa1 = *(const half8*)(A1S + r * 40 + lgrp * 8);
        half8 fa2 = *(const half8*)(A2S + r * 40 + lgrp * 8);
#pragma unroll
        for (int q = 0; q < 2; ++q) {
          acc1[mt][q] = __builtin_amdgcn_mfma_f32_16x16x32_f16(fa1, fz[q], acc1[mt][q], 0, 0, 0);
          acc2[mt][q] = __builtin_amdgcn_mfma_f32_16x16x32_f16(fa2, fz[q], acc2[mt][q], 0, 0, 0);
        }
      }
    }
    float* Zb = p.Zg + (size_t)b * 800 * ldz;
    float* o1 = Zb + P + outOff;
    float* o2 = Zb + 2 * P + outOff;
#pragma unroll
    for (int mt = 0; mt < 4; ++mt)
#pragma unroll
      for (int q = 0; q < 2; ++q) {
        int c = colBase + waveN * 32 + q * 16 + lrow;
        if (c < inW) {
#pragma unroll
          for (int j = 0; j < 4; ++j) {
            int r = rowBase + waveM * 64 + mt * 16 + lgrp * 4 + j;
            if (r < 800) {
              o1[(size_t)r * ldz + c] = acc1[mt][q][j];
              o2[(size_t)r * ldz + c] = acc2[mt][q][j];
            }
          }
        }
      }
  }
}

// ================= gate proj (fp16x3 MFMA + GRU gate epilogue) =================
template <int LAYER>
__device__ void d_gate(const Params& p, char* sm, int dec) {
  const int P = LAYER ? 128 : 68;
  const int ldz = 3 * P, K3 = 3 * P;
  const int Kp = LAYER ? 384 : 224;
  const int Pin = LAYER ? 64 : 4;
  int widx = dec * 4 + LAYER * 2;
  const f16_t* Wth = p.wh[widx];
  const f16_t* Wtl = p.wl[widx];
  const float* bias = p.bia[widx];
  float* h = LAYER ? p.h1 : p.h0;
  const float* Z = p.Zg;
  f16_t* ZhS = (f16_t*)sm;
  f16_t* ZlS = ZhS + 5120;
  f16_t* WhS = ZlS + 5120;
  f16_t* WlS = WhS + 5120;
  int tid = threadIdx.x;
  int lane = tid & 63, wid = tid >> 6;
  int waveM = wid >> 1, waveN = wid & 1;
  int lrow = lane & 15, lgrp = lane >> 4;
  int zrow = tid >> 1, zhalf = tid & 1;
  int wcol = tid >> 1, whalf = tid & 1;
  for (int tile = blockIdx.x; tile < 400; tile += gridDim.x) {
    int rowBase = tile * 128;
    f32x4 aM[4][4], aC[4][4];
#pragma unroll
    for (int mt = 0; mt < 4; ++mt)
#pragma unroll
      for (int q = 0; q < 4; ++q) {
        aM[mt][q] = (f32x4){0.f, 0.f, 0.f, 0.f};
        aC[mt][q] = (f32x4){0.f, 0.f, 0.f, 0.f};
      }
    for (int k0 = 0; k0 < Kp; k0 += 32) {
      __syncthreads();
      {
        const float* src = Z + (size_t)(rowBase + zrow) * ldz + k0 + zhalf * 16;
        f16_t hb[16], lb[16];
        if (k0 + 32 <= K3) {
#pragma unroll
          for (int v4 = 0; v4 < 4; ++v4) {
            float4 v = *(const float4*)(src + v4 * 4);
            float vv[4] = {v.x, v.y, v.z, v.w};
#pragma unroll
            for (int j = 0; j < 4; ++j) {
              f16_t hh = (f16_t)vv[j];
              hb[v4 * 4 + j] = hh;
              lb[v4 * 4 + j] = (f16_t)((vv[j] - (float)hh) * 2048.0f);
            }
          }
        } else {
#pragma unroll
          for (int i = 0; i < 16; ++i) {
            int kk = k0 + zhalf * 16 + i;
            float a = (kk < K3) ? src[i] : 0.f;
            f16_t hh = (f16_t)a;
            hb[i] = hh;
            lb[i] = (f16_t)((a - (float)hh) * 2048.0f);
          }
        }
        int s = zrow * 40 + zhalf * 16;
        *(half8*)(ZhS + s) = *(half8*)hb;
        *(half8*)(ZhS + s + 8) = *(half8*)(hb + 8);
        *(half8*)(ZlS + s) = *(half8*)lb;
        *(half8*)(ZlS + s + 8) = *(half8*)(lb + 8);
      }
      {
        size_t g = (size_t)wcol * Kp + k0 + whalf * 16;
        uint4 h0v = *(const uint4*)(Wth + g);
        uint4 h1v = *(const uint4*)(Wth + g + 8);
        uint4 l0v = *(const uint4*)(Wtl + g);
        uint4 l1v = *(const uint4*)(Wtl + g + 8);
        int s = wcol * 40 + whalf * 16;
        *(uint4*)(WhS + s) = h0v;
        *(uint4*)(WhS + s + 8) = h1v;
        *(uint4*)(WlS + s) = l0v;
        *(uint4*)(WlS + s + 8) = l1v;
      }
      __syncthreads();
      half8 fwh[4], fwl[4];
#pragma unroll
      for (int q = 0; q < 4; ++q) {
        int c = waveN * 64 + q * 16 + lrow;
        fwh[q] = *(const half8*)(WhS + c * 40 + lgrp * 8);
        fwl[q] = *(const half8*)(WlS + c * 40 + lgrp * 8);
      }
#pragma unroll
      for (int mt = 0; mt < 4; ++mt) {
        int r = waveM * 64 + mt * 16 + lrow;
        half8 fzh = *(const half8*)(ZhS + r * 40 + lgrp * 8);
        half8 fzl = *(const half8*)(ZlS + r * 40 + lgrp * 8);
#pragma unroll
        for (int q = 0; q < 4; ++q) {
          aM[mt][q] = __builtin_amdgcn_mfma_f32_16x16x32_f16(fzh, fwh[q], aM[mt][q], 0, 0, 0);
          aC[mt][q] = __builtin_amdgcn_mfma_f32_16x16x32_f16(fzh, fwl[q], aC[mt][q], 0, 0, 0);
          aC[mt][q] = __builtin_amdgcn_mfma_f32_16x16x32_f16(fzl, fwh[q], aC[mt][q], 0, 0, 0);
        }
      }
    }
#pragma unroll
    for (int mt = 0; mt < 4; ++mt)
#pragma unroll
      for (int q = 0; q < 4; ++q) {
        int col = waveN * 64 + q * 16 + lrow;
#pragma unroll
        for (int j = 0; j < 4; ++j) {
          int row = rowBase + waveM * 64 + mt * 16 + lgrp * 4 + j;
          float v = aM[mt][q][j] + aC[mt][q][j] * (1.0f / 2048.0f) + bias[col];
          if (col < 64) {
            p.U[(size_t)row * 64 + col] = sigm(v);
          } else {
            int jj = col - 64;
            p.Zg[(size_t)row * ldz + Pin + jj] = sigm(v) * h[(size_t)row * 64 + jj];
          }
        }
      }
  }
}

// ================= candidate proj (fp16x3 MFMA + GRU update epilogue) =================
template <int LAYER>
__device__ void d_cand(const Params& p, char* sm, int dec) {
  const int P = LAYER ? 128 : 68;
  const int ldz = 3 * P, K3 = 3 * P;
  const int Kp = LAYER ? 384 : 224;
  int widx = dec * 4 + LAYER * 2 + 1;
  const f16_t* Wth = p.wh[widx];
  const f16_t* Wtl = p.wl[widx];
  const float* bias = p.bia[widx];
  float* h = LAYER ? p.h1 : p.h0;
  const float* Z = p.Zg;
  f16_t* ZhS = (f16_t*)sm;          // 256*40
  f16_t* ZlS = ZhS + 10240;
  f16_t* WhS = ZlS + 10240;         // 64*40
  f16_t* WlS = WhS + 2560;
  int tid = threadIdx.x;
  int lane = tid & 63, wid = tid >> 6;
  int lrow = lane & 15, lgrp = lane >> 4;
  int wcol = tid >> 2, wq = tid & 3;
  for (int tile = blockIdx.x; tile < 200; tile += gridDim.x) {
    int rowBase = tile * 256;
    f32x4 aM[4][4], aC[4][4];
#pragma unroll
    for (int mt = 0; mt < 4; ++mt)
#pragma unroll
      for (int q = 0; q < 4; ++q) {
        aM[mt][q] = (f32x4){0.f, 0.f, 0.f, 0.f};
        aC[mt][q] = (f32x4){0.f, 0.f, 0.f, 0.f};
      }
    for (int k0 = 0; k0 < Kp; k0 += 32) {
      __syncthreads();
      {
        const float* src = Z + (size_t)(rowBase + tid) * ldz + k0;
        f16_t hb[32], lb[32];
        if (k0 + 32 <= K3) {
#pragma unroll
          for (int v4 = 0; v4 < 8; ++v4) {
            float4 v = *(const float4*)(src + v4 * 4);
            float vv[4] = {v.x, v.y, v.z, v.w};
#pragma unroll
            for (int j = 0; j < 4; ++j) {
              f16_t hh = (f16_t)vv[j];
              hb[v4 * 4 + j] = hh;
              lb[v4 * 4 + j] = (f16_t)((vv[j] - (float)hh) * 2048.0f);
            }
          }
        } else {
#pragma unroll
          for (int i = 0; i < 32; ++i) {
            int kk = k0 + i;
            float a = (kk < K3) ? src[i] : 0.f;
            f16_t hh = (f16_t)a;
            hb[i] = hh;
            lb[i] = (f16_t)((a - (float)hh) * 2048.0f);
          }
        }
        int s = tid * 40;
#pragma unroll
        for (int g = 0; g < 4; ++g) {
          *(half8*)(ZhS + s + g * 8) = *(half8*)(hb + g * 8);
          *(half8*)(ZlS + s + g * 8) = *(half8*)(lb + g * 8);
        }
      }
      {
        size_t g = (size_t)wcol * Kp + k0 + wq * 8;
        uint4 hv = *(const uint4*)(Wth + g);
        uint4 lv = *(const uint4*)(Wtl + g);
        int s = wcol * 40 + wq * 8;
        *(uint4*)(WhS + s) = hv;
        *(uint4*)(WlS + s) = lv;
      }
      __syncthreads();
      half8 fwh[4], fwl[4];
#pragma unroll
      for (int q = 0; q < 4; ++q) {
        int c = q * 16 + lrow;
        fwh[q] = *(const half8*)(WhS + c * 40 + lgrp * 8);
        fwl[q] = *(const half8*)(WlS + c * 40 + lgrp * 8);
      }
#pragma unroll
      for (int mt = 0; mt < 4; ++mt) {
        int r = wid * 64 + mt * 16 + lrow;
        half8 fzh = *(const half8*)(ZhS + r * 40 + lgrp * 8);
        half8 fzl = *(const half8*)(ZlS + r * 40 + lgrp * 8);
#pragma unroll
        for (int q = 0; q < 4; ++q) {
          aM[mt][q] = __builtin_amdgcn_mfma_f32_16x16x32_f16(fzh, fwh[q], aM[mt][q], 0, 0, 0);
          aC[mt][q] = __builtin_amdgcn_mfma_f32_16x16x32_f16(fzh, fwl[q], aC[mt][q], 0, 0, 0);
          aC[mt][q] = __builtin_amdgcn_mfma_f32_16x16x32_f16(fzl, fwh[q], aC[mt][q], 0, 0, 0);
        }
      }
    }
#pragma unroll
    for (int mt = 0; mt < 4; ++mt)
#pragma unroll
      for (int q = 0; q < 4; ++q) {
        int col = q * 16 + lrow;
#pragma unroll
        for (int j = 0; j < 4; ++j) {
          int row = rowBase + wid * 64 + mt * 16 + lgrp * 4 + j;
          float v = aM[mt][q][j] + aC[mt][q][j] * (1.0f / 2048.0f) + bias[col];
          float cc = tanhf(v);
          float u = p.U[(size_t)row * 64 + col];
          float hv = h[(size_t)row * 64 + col];
          h[(size_t)row * 64 + col] = (1.f - u) * hv + u * cc;
        }
      }
  }
}

// ================= memory-attention =================

__device__ void d_memq1(const Params& p) {
  int gwid = (blockIdx.x * blockDim.x + threadIdx.x) >> 6;
  int nw = (gridDim.x * blockDim.x) >> 6;
  int lane = threadIdx.x & 63;
  for (int tile = gwid; tile < 1024; tile += nw) {
    int cx = tile & 15, b = tile >> 4;
    float acc[8] = {};
    const float* hrow = p.h1 + (size_t)b * 51200 + cx * 3200;
    const float* wbase = p.Wa + (size_t)cx * 3200 * 8;
    for (int i = lane; i < 3200; i += 64) {
      float hv = hrow[i];
      const float* wr = wbase + (size_t)i * 8;
#pragma unroll
      for (int j = 0; j < 8; ++j) acc[j] += hv * wr[j];
    }
#pragma unroll
    for (int s = 1; s < 64; s <<= 1) {
#pragma unroll
      for (int j = 0; j < 8; ++j) acc[j] += __shfl_xor(acc[j], s);
    }
    if (lane == 0) {
#pragma unroll
      for (int j = 0; j < 8; ++j) p.partial[((size_t)b * 16 + cx) * 8 + j] = acc[j];
    }
  }
}

__device__ void d_outphase(const Params& p, char* sm, int t) {
  float* attv = (float*)sm;  // 64*8
  int tid = threadIdx.x;
  if (tid < 64) {
    int b = tid;
    float q[8] = {};
    for (int cx = 0; cx < 16; ++cx)
#pragma unroll
      for (int j = 0; j < 8; ++j) q[j] += p.partial[((size_t)b * 16 + cx) * 8 + j];
    float sco[4], mx = -1e30f;
#pragma unroll
    for (int m = 0; m < 4; ++m) {
      float s = 0.f;
#pragma unroll
      for (int d = 0; d < 8; ++d) s += q[d] * p.mem[m * 8 + d];
      sco[m] = s;
      mx = fmaxf(mx, s);
    }
    float se = 0.f;
#pragma unroll
    for (int m = 0; m < 4; ++m) { sco[m] = expf(sco[m] - mx); se += sco[m]; }
#pragma unroll
    for (int d = 0; d < 8; ++d) {
      float av = 0.f;
#pragma unroll
      for (int m = 0; m < 4; ++m) av += (sco[m] / se) * p.mem[m * 8 + d];
      attv[b * 8 + d] = av;
    }
  }
  __syncthreads();
  int nt = gridDim.x * blockDim.x, id = blockIdx.x * blockDim.x + tid;
  for (int row = id; row < ROWS_; row += nt) {
    int b = row / 800, n = row - b * 800;
    const float* av = attv + b * 8;
    float attm[8];
#pragma unroll
    for (int d = 0; d < 8; ++d) {
      float s = 0.f;
#pragma unroll
      for (int m = 0; m < 8; ++m) s += av[m] * p.fc[(size_t)m * 6400 + n * 8 + d];
      attm[d] = s;
    }
    float o0 = p.projb[0], o1 = p.projb[1];
#pragma unroll
    for (int j4 = 0; j4 < 16; ++j4) {
      float4 h4 = *(const float4*)(p.h1 + (size_t)row * 64 + j4 * 4);
      float hv[4] = {h4.x, h4.y, h4.z, h4.w};
#pragma unroll
      for (int i = 0; i < 4; ++i) {
        o0 += hv[i] * p.projW[(j4 * 4 + i) * 2 + 0];
        o1 += hv[i] * p.projW[(j4 * 4 + i) * 2 + 1];
      }
    }
#pragma unroll
    for (int d = 0; d < 8; ++d) {
      o0 += attm[d] * p.projW[(64 + d) * 2 + 0];
      o1 += attm[d] * p.projW[(64 + d) * 2 + 1];
    }
    size_t base = ((size_t)(b * 12 + t) * 800 + n) * 2;
    p.dout[base + 0] = fmaxf(o0, 0.f);
    p.dout[base + 1] = fmaxf(o1, 0.f);
  }
}

// ================= mega kernel =================

template <int LAYER>
__device__ void run_cell(const Params& p, cg::grid_group& grid, char* sm, int mode, int dec, int t) {
  d_pack<LAYER>(p, mode, t);
  d_graph<LAYER>(p, sm, mode, t, LAYER ? 128 : 68, 0);
  grid.sync();
  d_gate<LAYER>(p, sm, dec);
  grid.sync();
  d_graph<LAYER>(p, sm, 3, t, 64, LAYER ? 64 : 4);
  grid.sync();
  d_cand<LAYER>(p, sm, dec);
  grid.sync();
}

__global__ void __launch_bounds__(256, 2) meganet(Params p) {
  cg::grid_group grid = cg::this_grid();
  __shared__ __align__(16) char sm[51456];
  d_zero(p);
  d_transp(p);
  for (int w = 0; w < 8; ++w) {
    int layer = (w >> 1) & 1, cand = w & 1;
    d_wsplit(p.Wraw[w], p.wh[w], p.wl[w], layer ? 128 : 68, cand ? 64 : 128, layer ? 384 : 224);
  }
  d_mlp_hid(p, p.t_x, p.hidb);
  d_mlp_hid(p, p.t_y, p.hidb + 7680);
  grid.sync();
  d_t2(p, sm);
  d_mlp_out(p, p.hidb, p.txe);
  d_mlp_out(p, p.hidb + 7680, p.tye);
  grid.sync();
  for (int t = 0; t < 12; ++t) {
    run_cell<0>(p, grid, sm, 0, 0, t);
    run_cell<1>(p, grid, sm, 2, 0, t);
  }
  for (int t = 0; t < 12; ++t) {
    run_cell<0>(p, grid, sm, 1, 1, t);
    run_cell<1>(p, grid, sm, 2, 1, t);
    d_memq1(p);
    grid.sync();
    d_outphase(p, sm, t);
    grid.sync();
  }
}

// ================= fallback wrappers (discrete kernels, same phases) =================

__global__ void __launch_bounds__(256, 2) k_p0(Params p) {
  d_zero(p);
  d_transp(p);
  for (int w = 0; w < 8; ++w) {
    int layer = (w >> 1) & 1, cand = w & 1;
    d_wsplit(p.Wraw[w], p.wh[w], p.wl[w], layer ? 128 : 68, cand ? 64 : 128, layer ? 384 : 224);
  }
  d_mlp_hid(p, p.t_x, p.hidb);
  d_mlp_hid(p, p.t_y, p.hidb + 7680);
}
__global__ void __launch_bounds__(256, 2) k_p1(Params p) {
  __shared__ __align__(16) char sm[8704];
  d_t2(p, sm);
  d_mlp_out(p, p.hidb, p.txe);
  d_mlp_out(p, p.hidb + 7680, p.tye);
}
template <int LAYER>
__global__ void __launch_bounds__(256, 2) k_c1(Params p, int mode, int t) {
  __shared__ __align__(16) char sm[25600];
  d_pack<LAYER>(p, mode, t);
  d_graph<LAYER>(p, sm, mode, t, LAYER ? 128 : 68, 0);
}
template <int LAYER>
__global__ void __launch_bounds__(256, 2) k_c2(Params p, int dec) {
  __shared__ __align__(16) char sm[40960];
  d_gate<LAYER>(p, sm, dec);
}
template <int LAYER>
__global__ void __launch_bounds__(256, 2) k_c3(Params p, int t) {
  __shared__ __align__(16) char sm[25600];
  d_graph<LAYER>(p, sm, 3, t, 64, LAYER ? 64 : 4);
}
template <int LAYER>
__global__ void __launch_bounds__(256, 2) k_c4(Params p, int dec) {
  __shared__ __align__(16) char sm[51456];
  d_cand<LAYER>(p, sm, dec);
}
__global__ void __launch_bounds__(256, 2) k_m1(Params p) { d_memq1(p); }
__global__ void __launch_bounds__(256, 2) k_m2(Params p, int t) {
  __shared__ __align__(16) char sm[2048];
  d_outphase(p, sm, t);
}

// ================= host =================

extern "C" void kernel_launch(void* const* d_in, const int* in_sizes, int n_in,
                              void* d_out, int out_size, void* d_ws, size_t ws_size,
                              hipStream_t stream) {
  Params P;
  P.x_seq = (const float*)d_in[0];
  P.t_x = (const float*)d_in[1];
  P.t_y = (const float*)d_in[2];
  P.G = (const float*)d_in[3];
  // idx = dec*4 + layer*2 + cand
  P.Wraw[0] = (const float*)d_in[4];  P.bia[0] = (const float*)d_in[5];
  P.Wraw[1] = (const float*)d_in[6];  P.bia[1] = (const float*)d_in[7];
  P.Wraw[2] = (const float*)d_in[8];  P.bia[2] = (const float*)d_in[9];
  P.Wraw[3] = (const float*)d_in[10]; P.bia[3] = (const float*)d_in[11];
  P.Wraw[4] = (const float*)d_in[12]; P.bia[4] = (const float*)d_in[13];
  P.Wraw[5] = (const float*)d_in[14]; P.bia[5] = (const float*)d_in[15];
  P.Wraw[6] = (const float*)d_in[16]; P.bia[6] = (const float*)d_in[17];
  P.Wraw[7] = (const float*)d_in[18]; P.bia[7] = (const float*)d_in[19];
  P.mW1 = (const float*)d_in[20];
  P.mb1 = (const float*)d_in[21];
  P.mW2 = (const float*)d_in[22];
  P.mb2 = (const float*)d_in[23];
  P.mem = (const float*)d_in[24];
  P.Wa = (const float*)d_in[25];
  P.fc = (const float*)d_in[26];
  P.projW = (const float*)d_in[27];
  P.projb = (const float*)d_in[28];
  P.dout = (float*)d_out;

  float* ws = (float*)d_ws;
  size_t off = 0;
  auto alloc = [&](size_t nel) { float* q = ws + off; off += nel; return q; };
  P.A1 = alloc(640000);
  P.A1h = (f16_t*)alloc(320000);
  P.A2h = (f16_t*)alloc(320000);
  P.Zg = alloc((size_t)ROWS_ * 384);
  P.U = alloc((size_t)ROWS_ * 64);
  P.h0 = alloc((size_t)ROWS_ * 64);
  P.h1 = alloc((size_t)ROWS_ * 64);
  P.txe = alloc((size_t)768 * 1600);
  P.tye = alloc((size_t)768 * 1600);
  P.hidb = alloc(15360);
  P.partial = alloc(8192);
  const int kpnc[8] = {224 * 128, 224 * 64, 384 * 128, 384 * 64, 224 * 128, 224 * 64, 384 * 128, 384 * 64};
  for (int w = 0; w < 8; ++w) {
    P.wh[w] = (f16_t*)alloc((kpnc[w] + 1) / 2);
    P.wl[w] = (f16_t*)alloc((kpnc[w] + 1) / 2);
  }

  void* kargs[] = {(void*)&P};
  hipError_t err = hipLaunchCooperativeKernel((void*)meganet, dim3(512), dim3(256), kargs, 0, stream);
  if (err != hipSuccess) {
    (void)hipGetLastError();  // clear sticky error, use discrete-kernel fallback
    k_p0<<<512, 256, 0, stream>>>(P);
    k_p1<<<512, 256, 0, stream>>>(P);
    for (int t = 0; t < 12; ++t) {
      k_c1<0><<<512, 256, 0, stream>>>(P, 0, t);
      k_c2<0><<<512, 256, 0, stream>>>(P, 0);
      k_c3<0><<<512, 256, 0, stream>>>(P, t);
      k_c4<0><<<512, 256, 0, stream>>>(P, 0);
      k_c1<1><<<512, 256, 0, stream>>>(P, 2, t);
      k_c2<1><<<512, 256, 0, stream>>>(P, 0);
      k_c3<1><<<512, 256, 0, stream>>>(P, t);
      k_c4<1><<<512, 256, 0, stream>>>(P, 0);
    }
    for (int t = 0; t < 12; ++t) {
      k_c1<0><<<512, 256, 0, stream>>>(P, 1, t);
      k_c2<0><<<512, 256, 0, stream>>>(P, 1);
      k_c3<0><<<512, 256, 0, stream>>>(P, t);
      k_c4<0><<<512, 256, 0, stream>>>(P, 1);
      k_c1<1><<<512, 256, 0, stream>>>(P, 2, t);
      k_c2<1><<<512, 256, 0, stream>>>(P, 1);
      k_c3<1><<<512, 256, 0, stream>>>(P, t);
      k_c4<1><<<512, 256, 0, stream>>>(P, 1);
      k_m1<<<512, 256, 0, stream>>>(P);
      k_m2<<<512, 256, 0, stream>>>(P, t);
    }
  }
}

// Round 5
// 14907.826 us; speedup vs baseline: 2.3421x; 2.3421x over previous
//
#include <hip/hip_runtime.h>
#include <math.h>

#define ROWS_ 51200  // B*N = 64*800

typedef _Float16 f16_t;
typedef _Float16 half8 __attribute__((ext_vector_type(8)));
typedef float f32x4 __attribute__((ext_vector_type(4)));

struct Params {
  const float* x_seq; const float* t_x; const float* t_y; const float* G;
  const float* Wraw[8]; const float* bia[8];   // idx = dec*4 + layer*2 + cand
  const float* mW1; const float* mb1; const float* mW2; const float* mb2;
  const float* mem; const float* Wa; const float* fc; const float* projW; const float* projb;
  float* dout;
  float* A1; float* Zg; float* U; float* h0; float* h1;
  float* txe; float* tye; float* hidb; float* partial;
  f16_t* A1h; f16_t* A2h; f16_t* Apk1; f16_t* Apk2;
  f16_t* wh[8]; f16_t* wl[8];
};

__device__ __forceinline__ float sigm(float x) { return 1.0f / (1.0f + expf(-x)); }

// ================= prologue =================

__global__ void __launch_bounds__(256) k_p0(Params p) {
  int nt = gridDim.x * blockDim.x, id = blockIdx.x * blockDim.x + threadIdx.x;
  float4 z = {0.f, 0.f, 0.f, 0.f};
  for (int i = id; i < ROWS_ * 16; i += nt) { ((float4*)p.h0)[i] = z; ((float4*)p.h1)[i] = z; }
  for (int i = id; i < 640000; i += nt) {
    int m = i / 800, n = i - m * 800;
    float v = p.G[n * 800 + m];
    p.A1[i] = v;
    p.A1h[i] = (f16_t)v;
  }
  for (int w = 0; w < 8; ++w) {
    int layer = (w >> 1) & 1, cand = w & 1;
    int P = layer ? 128 : 68, NC = cand ? 64 : 128, Kp = layer ? 384 : 224;
    const float* W = p.Wraw[w];
    f16_t* Wth = p.wh[w];
    f16_t* Wtl = p.wl[w];
    for (int idx = id; idx < Kp * NC; idx += nt) {
      int i = idx / NC, c = idx - i * NC;
      float v = 0.f;
      if (i < 3 * P) {
        int k = i / P, pp = i - k * P;
        if (k == 0)
          v = W[(size_t)pp * NC + c] + 0.05f * (W[(size_t)(P + pp) * NC + c] + W[(size_t)(2 * P + pp) * NC + c]);
        else
          v = 0.95f * W[(size_t)i * NC + c];
      }
      f16_t h = (f16_t)v;
      Wth[(size_t)c * Kp + i] = h;
      Wtl[(size_t)c * Kp + i] = (f16_t)((v - (float)h) * 2048.0f);
    }
  }
  for (int idx = id; idx < 15360; idx += nt) {
    int half = idx / 7680, rem = idx - half * 7680;
    int r = rem / 10, j = rem - r * 10;
    const float* tin = half ? p.t_y : p.t_x;
    float a = p.mb1[j];
    for (int k = 0; k < 60; ++k) a += tin[(size_t)r * 60 + k] * p.mW1[k * 10 + j];
    p.hidb[idx] = a;
  }
}

// T2 = 2*A1@A1 - I (f16 out) + mlp_out
__global__ void __launch_bounds__(256) k_p1(Params p) {
  __shared__ float As[16 * 68];
  __shared__ float Bs[16 * 68];
  int tid = threadIdx.x, tx = tid & 15, ty = tid >> 4;
  const float* A = p.A1;
  for (int tile = blockIdx.x; tile < 169; tile += gridDim.x) {
    int bx = tile % 13, by = tile / 13;
    int rowBase = by * 64, colBase = bx * 64;
    float acc[4][4] = {};
    for (int k0 = 0; k0 < 800; k0 += 16) {
      __syncthreads();
      for (int e = tid; e < 1024; e += 256) {
        int r = e >> 4, c = e & 15;
        int gr = rowBase + r;
        As[c * 68 + r] = (gr < 800) ? A[gr * 800 + k0 + c] : 0.f;
      }
      for (int e = tid; e < 1024; e += 256) {
        int r = e >> 6, c = e & 63;
        int gc = colBase + c;
        Bs[r * 68 + c] = (gc < 800) ? A[(k0 + r) * 800 + gc] : 0.f;
      }
      __syncthreads();
#pragma unroll
      for (int kk = 0; kk < 16; ++kk) {
        float4 a4 = *(const float4*)&As[kk * 68 + ty * 4];
        float4 b4 = *(const float4*)&Bs[kk * 68 + tx * 4];
        float av[4] = {a4.x, a4.y, a4.z, a4.w};
        float bv[4] = {b4.x, b4.y, b4.z, b4.w};
#pragma unroll
        for (int i = 0; i < 4; ++i)
#pragma unroll
          for (int j = 0; j < 4; ++j) acc[i][j] += av[i] * bv[j];
      }
    }
#pragma unroll
    for (int i = 0; i < 4; ++i) {
      int m = rowBase + ty * 4 + i;
      if (m >= 800) continue;
#pragma unroll
      for (int j = 0; j < 4; ++j) {
        int n = colBase + tx * 4 + j;
        if (n < 800) p.A2h[m * 800 + n] = (f16_t)(2.f * acc[i][j] - (m == n ? 1.f : 0.f));
      }
    }
  }
  int nt = gridDim.x * blockDim.x, id = blockIdx.x * blockDim.x + threadIdx.x;
  for (int idx = id; idx < 2 * 768 * 1600; idx += nt) {
    int half = idx / (768 * 1600), rem = idx - half * (768 * 1600);
    int r = rem / 1600, o = rem - r * 1600;
    const float* hid = p.hidb + half * 7680;
    float* emb = half ? p.tye : p.txe;
    float a = p.mb2[o];
#pragma unroll
    for (int k = 0; k < 10; ++k) a += hid[r * 10 + k] * p.mW2[k * 1600 + o];
    emb[rem] = a;
  }
}

// pack A into k-panel layout: Apk[(k>>5)][m][k&31]
__global__ void __launch_bounds__(256) k_p2(Params p) {
  int nt = gridDim.x * blockDim.x, id = blockIdx.x * blockDim.x + threadIdx.x;
  for (int i = id; i < 640000; i += nt) {
    int m = i / 800, k = i - m * 800;
    size_t dst = (size_t)(k >> 5) * 25600 + m * 32 + (k & 31);
    p.Apk1[dst] = p.A1h[i];
    p.Apk2[dst] = p.A2h[i];
  }
}

// ================= source gather =================
// mode: 0 = layer0 enc, 1 = layer0 dec, 2 = layer1 [h0|h1], 3 = Zg rh slot
template <int LAYER>
__device__ __forceinline__ float zread(const Params& p, int mode, int t, int b, int n, int c) {
  const int ldz = LAYER ? 384 : 204;
  const int Pin = LAYER ? 64 : 4;
  size_t rn = (size_t)b * 800 + n;
  if (mode == 3) return p.Zg[rn * ldz + Pin + c];
  if (LAYER) return (c < 64) ? p.h0[rn * 64 + c] : p.h1[rn * 64 + (c - 64)];
  if (c >= 4) return p.h0[rn * 64 + (c - 4)];
  if (c < 2) {
    if (mode == 0) return p.x_seq[((size_t)(b * 12 + t) * 800 + n) * 2 + c];
    return (t == 0) ? 0.f : p.dout[((size_t)(b * 12 + (t - 1)) * 800 + n) * 2 + c];
  }
  const float* e = (mode == 0) ? p.txe : p.tye;
  return e[(size_t)(b * 12 + t) * 1600 + n * 2 + (c - 2)];
}

// ================= graph MFMA (both Chebyshev mats, pipelined, pack fused) =================
template <int LAYER>
__global__ void __launch_bounds__(256, 4) g_graph(Params p, int mode, int t, int inW, int outOff) {
  const int P = LAYER ? 128 : 68;
  const int ldz = 3 * P;
  __shared__ __align__(16) f16_t A1S[128 * 40];
  __shared__ __align__(16) f16_t A2S[128 * 40];
  __shared__ __align__(16) f16_t ZS[64 * 40];
  int tid = threadIdx.x;
  int lane = tid & 63, wid = tid >> 6;
  int waveM = wid >> 1, waveN = wid & 1;
  int lrow = lane & 15, lgrp = lane >> 4;
  int arow = tid >> 1, ahalf = tid & 1;
  int zc = tid & 63, zgrp = tid >> 6;
  int gx = (inW + 63) >> 6;
  int tile = blockIdx.x;
  int xb = tile % gx;
  int r2 = tile / gx;
  int yb = r2 % 7;
  int b = r2 / 7;
  int rowBase = yb * 128, colBase = xb * 64;
  int ar = rowBase + arow;
  if (ar > 799) ar = 799;
  bool zvalid = (colBase + zc) < inW;
  bool wr0 = (yb == 0) && (mode != 3) && zvalid;  // fused pack of plane0

  uint4 ra1[2], ra2[2];
  float rz[8];

  auto prefetch = [&](int ks) {
    size_t ao = ((size_t)ks * 800 + ar) * 32 + ahalf * 16;
    ra1[0] = *(const uint4*)(p.Apk1 + ao);
    ra1[1] = *(const uint4*)(p.Apk1 + ao + 8);
    ra2[0] = *(const uint4*)(p.Apk2 + ao);
    ra2[1] = *(const uint4*)(p.Apk2 + ao + 8);
    int k0 = ks * 32;
#pragma unroll
    for (int i = 0; i < 8; ++i) {
      int n = k0 + zgrp * 8 + i;
      rz[i] = zvalid ? zread<LAYER>(p, mode, t, b, n, colBase + zc) : 0.f;
    }
  };

  f32x4 acc1[4][2], acc2[4][2];
#pragma unroll
  for (int mt = 0; mt < 4; ++mt)
#pragma unroll
    for (int q = 0; q < 2; ++q) {
      acc1[mt][q] = (f32x4){0.f, 0.f, 0.f, 0.f};
      acc2[mt][q] = (f32x4){0.f, 0.f, 0.f, 0.f};
    }

  prefetch(0);
  for (int ks = 0; ks < 25; ++ks) {
    if (ks) __syncthreads();
    {
      int s = arow * 40 + ahalf * 16;
      *(uint4*)(A1S + s) = ra1[0];
      *(uint4*)(A1S + s + 8) = ra1[1];
      *(uint4*)(A2S + s) = ra2[0];
      *(uint4*)(A2S + s + 8) = ra2[1];
      half8 vh;
#pragma unroll
      for (int i = 0; i < 8; ++i) vh[i] = (f16_t)rz[i];
      *(half8*)(ZS + zc * 40 + zgrp * 8) = vh;
      if (wr0) {  // materialize plane0 for the proj GEMMs (coalesced across lanes)
        float* dst = p.Zg + ((size_t)b * 800 + ks * 32 + zgrp * 8) * ldz + colBase + zc;
#pragma unroll
        for (int i = 0; i < 8; ++i) dst[(size_t)i * ldz] = rz[i];
      }
    }
    if (ks + 1 < 25) prefetch(ks + 1);
    __syncthreads();
    half8 fz[2];
#pragma unroll
    for (int q = 0; q < 2; ++q) {
      int c = waveN * 32 + q * 16 + lrow;
      fz[q] = *(const half8*)(ZS + c * 40 + lgrp * 8);
    }
#pragma unroll
    for (int mt = 0; mt < 4; ++mt) {
      int r = waveM * 64 + mt * 16 + lrow;
      half8 fa1 = *(const half8*)(A1S + r * 40 + lgrp * 8);
      half8 fa2 = *(const half8*)(A2S + r * 40 + lgrp * 8);
#pragma unroll
      for (int q = 0; q < 2; ++q) {
        acc1[mt][q] = __builtin_amdgcn_mfma_f32_16x16x32_f16(fa1, fz[q], acc1[mt][q], 0, 0, 0);
        acc2[mt][q] = __builtin_amdgcn_mfma_f32_16x16x32_f16(fa2, fz[q], acc2[mt][q], 0, 0, 0);
      }
    }
  }

  float* Zb = p.Zg + (size_t)b * 800 * ldz;
  float* o1 = Zb + P + outOff;
  float* o2 = Zb + 2 * P + outOff;
#pragma unroll
  for (int mt = 0; mt < 4; ++mt)
#pragma unroll
    for (int q = 0; q < 2; ++q) {
      int c = colBase + waveN * 32 + q * 16 + lrow;
      if (c < inW) {
#pragma unroll
        for (int j = 0; j < 4; ++j) {
          int r = rowBase + waveM * 64 + mt * 16 + lgrp * 4 + j;
          if (r < 800) {
            o1[(size_t)r * ldz + c] = acc1[mt][q][j];
            o2[(size_t)r * ldz + c] = acc2[mt][q][j];
          }
        }
      }
    }
}

// ================= gate proj: 64 rows x 128 cols per block, pipelined =================
template <int LAYER>
__global__ void __launch_bounds__(256, 4) g_gate(Params p, int dec) {
  const int P = LAYER ? 128 : 68;
  const int ldz = 3 * P, K3 = 3 * P;
  const int Kp = LAYER ? 384 : 224;
  const int NK = Kp / 32;
  const int Pin = LAYER ? 64 : 4;
  int widx = dec * 4 + LAYER * 2;
  const f16_t* __restrict__ Wth = p.wh[widx];
  const f16_t* __restrict__ Wtl = p.wl[widx];
  const float* bias = p.bia[widx];
  float* h = LAYER ? p.h1 : p.h0;
  __shared__ __align__(16) f16_t ZhS[64 * 40];
  __shared__ __align__(16) f16_t ZlS[64 * 40];
  __shared__ __align__(16) f16_t WhS[128 * 40];
  __shared__ __align__(16) f16_t WlS[128 * 40];
  int tid = threadIdx.x;
  int lane = tid & 63, wid = tid >> 6;
  int lrow = lane & 15, lgrp = lane >> 4;
  int zrow = tid >> 2, zq = tid & 3;
  int wcol = tid >> 1, whalf = tid & 1;
  int rowBase = blockIdx.x * 64;

  float rz[8];
  uint4 rwh[2], rwl[2];

  auto prefetch = [&](int ks) {
    int k0 = ks * 32;
    const float* src = p.Zg + (size_t)(rowBase + zrow) * ldz + k0 + zq * 8;
    if (k0 + 32 <= K3) {
      float4 v0 = *(const float4*)src;
      float4 v1 = *(const float4*)(src + 4);
      rz[0] = v0.x; rz[1] = v0.y; rz[2] = v0.z; rz[3] = v0.w;
      rz[4] = v1.x; rz[5] = v1.y; rz[6] = v1.z; rz[7] = v1.w;
    } else {
#pragma unroll
      for (int i = 0; i < 8; ++i) {
        int kk = k0 + zq * 8 + i;
        rz[i] = (kk < K3) ? src[i] : 0.f;
      }
    }
    size_t g = (size_t)wcol * Kp + k0 + whalf * 16;
    rwh[0] = *(const uint4*)(Wth + g);
    rwh[1] = *(const uint4*)(Wth + g + 8);
    rwl[0] = *(const uint4*)(Wtl + g);
    rwl[1] = *(const uint4*)(Wtl + g + 8);
  };

  f32x4 aM[4][2], aC[4][2];
#pragma unroll
  for (int mt = 0; mt < 4; ++mt)
#pragma unroll
    for (int q = 0; q < 2; ++q) {
      aM[mt][q] = (f32x4){0.f, 0.f, 0.f, 0.f};
      aC[mt][q] = (f32x4){0.f, 0.f, 0.f, 0.f};
    }

  prefetch(0);
  for (int ks = 0; ks < NK; ++ks) {
    if (ks) __syncthreads();
    {
      f16_t hb[8], lb[8];
#pragma unroll
      for (int i = 0; i < 8; ++i) {
        f16_t hh = (f16_t)rz[i];
        hb[i] = hh;
        lb[i] = (f16_t)((rz[i] - (float)hh) * 2048.0f);
      }
      int s = zrow * 40 + zq * 8;
      *(half8*)(ZhS + s) = *(half8*)hb;
      *(half8*)(ZlS + s) = *(half8*)lb;
      int sw = wcol * 40 + whalf * 16;
      *(uint4*)(WhS + sw) = rwh[0];
      *(uint4*)(WhS + sw + 8) = rwh[1];
      *(uint4*)(WlS + sw) = rwl[0];
      *(uint4*)(WlS + sw + 8) = rwl[1];
    }
    if (ks + 1 < NK) prefetch(ks + 1);
    __syncthreads();
    half8 fwh[2], fwl[2];
#pragma unroll
    for (int q = 0; q < 2; ++q) {
      int c = wid * 32 + q * 16 + lrow;
      fwh[q] = *(const half8*)(WhS + c * 40 + lgrp * 8);
      fwl[q] = *(const half8*)(WlS + c * 40 + lgrp * 8);
    }
#pragma unroll
    for (int mt = 0; mt < 4; ++mt) {
      int r = mt * 16 + lrow;
      half8 fzh = *(const half8*)(ZhS + r * 40 + lgrp * 8);
      half8 fzl = *(const half8*)(ZlS + r * 40 + lgrp * 8);
#pragma unroll
      for (int q = 0; q < 2; ++q) {
        aM[mt][q] = __builtin_amdgcn_mfma_f32_16x16x32_f16(fzh, fwh[q], aM[mt][q], 0, 0, 0);
        aC[mt][q] = __builtin_amdgcn_mfma_f32_16x16x32_f16(fzh, fwl[q], aC[mt][q], 0, 0, 0);
        aC[mt][q] = __builtin_amdgcn_mfma_f32_16x16x32_f16(fzl, fwh[q], aC[mt][q], 0, 0, 0);
      }
    }
  }

#pragma unroll
  for (int mt = 0; mt < 4; ++mt)
#pragma unroll
    for (int q = 0; q < 2; ++q) {
      int col = wid * 32 + q * 16 + lrow;
#pragma unroll
      for (int j = 0; j < 4; ++j) {
        int row = rowBase + mt * 16 + lgrp * 4 + j;
        float v = aM[mt][q][j] + aC[mt][q][j] * (1.0f / 2048.0f) + bias[col];
        if (col < 64) {
          p.U[(size_t)row * 64 + col] = sigm(v);
        } else {
          int jj = col - 64;
          p.Zg[(size_t)row * ldz + Pin + jj] = sigm(v) * h[(size_t)row * 64 + jj];
        }
      }
    }
}

// ================= candidate proj: 128 rows x 64 cols per block, pipelined =================
template <int LAYER>
__global__ void __launch_bounds__(256, 4) g_cand(Params p, int dec) {
  const int P = LAYER ? 128 : 68;
  const int ldz = 3 * P, K3 = 3 * P;
  const int Kp = LAYER ? 384 : 224;
  const int NK = Kp / 32;
  int widx = dec * 4 + LAYER * 2 + 1;
  const f16_t* __restrict__ Wth = p.wh[widx];
  const f16_t* __restrict__ Wtl = p.wl[widx];
  const float* bias = p.bia[widx];
  float* h = LAYER ? p.h1 : p.h0;
  __shared__ __align__(16) f16_t ZhS[128 * 40];
  __shared__ __align__(16) f16_t ZlS[128 * 40];
  __shared__ __align__(16) f16_t WhS[64 * 40];
  __shared__ __align__(16) f16_t WlS[64 * 40];
  int tid = threadIdx.x;
  int lane = tid & 63, wid = tid >> 6;
  int waveM = wid >> 1, waveN = wid & 1;
  int lrow = lane & 15, lgrp = lane >> 4;
  int zrow = tid >> 1, zhalf = tid & 1;
  int wcol = tid >> 2, wq = tid & 3;
  int rowBase = blockIdx.x * 128;

  float rz[16];
  uint4 rwh, rwl;

  auto prefetch = [&](int ks) {
    int k0 = ks * 32;
    const float* src = p.Zg + (size_t)(rowBase + zrow) * ldz + k0 + zhalf * 16;
    if (k0 + 32 <= K3) {
#pragma unroll
      for (int v4 = 0; v4 < 4; ++v4) {
        float4 v = *(const float4*)(src + v4 * 4);
        rz[v4 * 4 + 0] = v.x; rz[v4 * 4 + 1] = v.y; rz[v4 * 4 + 2] = v.z; rz[v4 * 4 + 3] = v.w;
      }
    } else {
#pragma unroll
      for (int i = 0; i < 16; ++i) {
        int kk = k0 + zhalf * 16 + i;
        rz[i] = (kk < K3) ? src[i] : 0.f;
      }
    }
    size_t g = (size_t)wcol * Kp + k0 + wq * 8;
    rwh = *(const uint4*)(Wth + g);
    rwl = *(const uint4*)(Wtl + g);
  };

  f32x4 aM[4][2], aC[4][2];
#pragma unroll
  for (int mt = 0; mt < 4; ++mt)
#pragma unroll
    for (int q = 0; q < 2; ++q) {
      aM[mt][q] = (f32x4){0.f, 0.f, 0.f, 0.f};
      aC[mt][q] = (f32x4){0.f, 0.f, 0.f, 0.f};
    }

  prefetch(0);
  for (int ks = 0; ks < NK; ++ks) {
    if (ks) __syncthreads();
    {
      f16_t hb[16], lb[16];
#pragma unroll
      for (int i = 0; i < 16; ++i) {
        f16_t hh = (f16_t)rz[i];
        hb[i] = hh;
        lb[i] = (f16_t)((rz[i] - (float)hh) * 2048.0f);
      }
      int s = zrow * 40 + zhalf * 16;
      *(half8*)(ZhS + s) = *(half8*)hb;
      *(half8*)(ZhS + s + 8) = *(half8*)(hb + 8);
      *(half8*)(ZlS + s) = *(half8*)lb;
      *(half8*)(ZlS + s + 8) = *(half8*)(lb + 8);
      int sw = wcol * 40 + wq * 8;
      *(uint4*)(WhS + sw) = rwh;
      *(uint4*)(WlS + sw) = rwl;
    }
    if (ks + 1 < NK) prefetch(ks + 1);
    __syncthreads();
    half8 fwh[2], fwl[2];
#pragma unroll
    for (int q = 0; q < 2; ++q) {
      int c = waveN * 32 + q * 16 + lrow;
      fwh[q] = *(const half8*)(WhS + c * 40 + lgrp * 8);
      fwl[q] = *(const half8*)(WlS + c * 40 + lgrp * 8);
    }
#pragma unroll
    for (int mt = 0; mt < 4; ++mt) {
      int r = waveM * 64 + mt * 16 + lrow;
      half8 fzh = *(const half8*)(ZhS + r * 40 + lgrp * 8);
      half8 fzl = *(const half8*)(ZlS + r * 40 + lgrp * 8);
#pragma unroll
      for (int q = 0; q < 2; ++q) {
        aM[mt][q] = __builtin_amdgcn_mfma_f32_16x16x32_f16(fzh, fwh[q], aM[mt][q], 0, 0, 0);
        aC[mt][q] = __builtin_amdgcn_mfma_f32_16x16x32_f16(fzh, fwl[q], aC[mt][q], 0, 0, 0);
        aC[mt][q] = __builtin_amdgcn_mfma_f32_16x16x32_f16(fzl, fwh[q], aC[mt][q], 0, 0, 0);
      }
    }
  }

#pragma unroll
  for (int mt = 0; mt < 4; ++mt)
#pragma unroll
    for (int q = 0; q < 2; ++q) {
      int col = waveN * 32 + q * 16 + lrow;
#pragma unroll
      for (int j = 0; j < 4; ++j) {
        int row = rowBase + waveM * 64 + mt * 16 + lgrp * 4 + j;
        float v = aM[mt][q][j] + aC[mt][q][j] * (1.0f / 2048.0f) + bias[col];
        float cc = tanhf(v);
        float u = p.U[(size_t)row * 64 + col];
        float hv = h[(size_t)row * 64 + col];
        h[(size_t)row * 64 + col] = (1.f - u) * hv + u * cc;
      }
    }
}

// ================= memory attention =================

__global__ void __launch_bounds__(256) k_m1(Params p) {
  int gwid = (blockIdx.x * blockDim.x + threadIdx.x) >> 6;
  int nw = (gridDim.x * blockDim.x) >> 6;
  int lane = threadIdx.x & 63;
  for (int tile = gwid; tile < 1024; tile += nw) {
    int cx = tile & 15, b = tile >> 4;
    float acc[8] = {};
    const float* hrow = p.h1 + (size_t)b * 51200 + cx * 3200;
    const float* wbase = p.Wa + (size_t)cx * 3200 * 8;
    for (int i = lane; i < 3200; i += 64) {
      float hv = hrow[i];
      const float* wr = wbase + (size_t)i * 8;
#pragma unroll
      for (int j = 0; j < 8; ++j) acc[j] += hv * wr[j];
    }
#pragma unroll
    for (int s = 1; s < 64; s <<= 1) {
#pragma unroll
      for (int j = 0; j < 8; ++j) acc[j] += __shfl_xor(acc[j], s);
    }
    if (lane == 0) {
#pragma unroll
      for (int j = 0; j < 8; ++j) p.partial[((size_t)b * 16 + cx) * 8 + j] = acc[j];
    }
  }
}

__global__ void __launch_bounds__(256) k_m2(Params p, int t) {
  __shared__ float attv[512];
  int tid = threadIdx.x;
  if (tid < 64) {
    int b = tid;
    float q[8] = {};
    for (int cx = 0; cx < 16; ++cx)
#pragma unroll
      for (int j = 0; j < 8; ++j) q[j] += p.partial[((size_t)b * 16 + cx) * 8 + j];
    float sco[4], mx = -1e30f;
#pragma unroll
    for (int m = 0; m < 4; ++m) {
      float s = 0.f;
#pragma unroll
      for (int d = 0; d < 8; ++d) s += q[d] * p.mem[m * 8 + d];
      sco[m] = s;
      mx = fmaxf(mx, s);
    }
    float se = 0.f;
#pragma unroll
    for (int m = 0; m < 4; ++m) { sco[m] = expf(sco[m] - mx); se += sco[m]; }
#pragma unroll
    for (int d = 0; d < 8; ++d) {
      float av = 0.f;
#pragma unroll
      for (int m = 0; m < 4; ++m) av += (sco[m] / se) * p.mem[m * 8 + d];
      attv[b * 8 + d] = av;
    }
  }
  __syncthreads();
  int nt = gridDim.x * blockDim.x, id = blockIdx.x * blockDim.x + tid;
  for (int row = id; row < ROWS_; row += nt) {
    int b = row / 800, n = row - b * 800;
    const float* av = attv + b * 8;
    float attm[8];
#pragma unroll
    for (int d = 0; d < 8; ++d) {
      float s = 0.f;
#pragma unroll
      for (int m = 0; m < 8; ++m) s += av[m] * p.fc[(size_t)m * 6400 + n * 8 + d];
      attm[d] = s;
    }
    float o0 = p.projb[0], o1 = p.projb[1];
#pragma unroll
    for (int j4 = 0; j4 < 16; ++j4) {
      float4 h4 = *(const float4*)(p.h1 + (size_t)row * 64 + j4 * 4);
      float hv[4] = {h4.x, h4.y, h4.z, h4.w};
#pragma unroll
      for (int i = 0; i < 4; ++i) {
        o0 += hv[i] * p.projW[(j4 * 4 + i) * 2 + 0];
        o1 += hv[i] * p.projW[(j4 * 4 + i) * 2 + 1];
      }
    }
#pragma unroll
    for (int d = 0; d < 8; ++d) {
      o0 += attm[d] * p.projW[(64 + d) * 2 + 0];
      o1 += attm[d] * p.projW[(64 + d) * 2 + 1];
    }
    size_t base = ((size_t)(b * 12 + t) * 800 + n) * 2;
    p.dout[base + 0] = fmaxf(o0, 0.f);
    p.dout[base + 1] = fmaxf(o1, 0.f);
  }
}

// ================= host =================

extern "C" void kernel_launch(void* const* d_in, const int* in_sizes, int n_in,
                              void* d_out, int out_size, void* d_ws, size_t ws_size,
                              hipStream_t stream) {
  Params P;
  P.x_seq = (const float*)d_in[0];
  P.t_x = (const float*)d_in[1];
  P.t_y = (const float*)d_in[2];
  P.G = (const float*)d_in[3];
  P.Wraw[0] = (const float*)d_in[4];  P.bia[0] = (const float*)d_in[5];
  P.Wraw[1] = (const float*)d_in[6];  P.bia[1] = (const float*)d_in[7];
  P.Wraw[2] = (const float*)d_in[8];  P.bia[2] = (const float*)d_in[9];
  P.Wraw[3] = (const float*)d_in[10]; P.bia[3] = (const float*)d_in[11];
  P.Wraw[4] = (const float*)d_in[12]; P.bia[4] = (const float*)d_in[13];
  P.Wraw[5] = (const float*)d_in[14]; P.bia[5] = (const float*)d_in[15];
  P.Wraw[6] = (const float*)d_in[16]; P.bia[6] = (const float*)d_in[17];
  P.Wraw[7] = (const float*)d_in[18]; P.bia[7] = (const float*)d_in[19];
  P.mW1 = (const float*)d_in[20];
  P.mb1 = (const float*)d_in[21];
  P.mW2 = (const float*)d_in[22];
  P.mb2 = (const float*)d_in[23];
  P.mem = (const float*)d_in[24];
  P.Wa = (const float*)d_in[25];
  P.fc = (const float*)d_in[26];
  P.projW = (const float*)d_in[27];
  P.projb = (const float*)d_in[28];
  P.dout = (float*)d_out;

  float* ws = (float*)d_ws;
  size_t off = 0;
  auto alloc = [&](size_t nel) { float* q = ws + off; off += nel; return q; };
  P.A1 = alloc(640000);
  P.A1h = (f16_t*)alloc(320000);
  P.A2h = (f16_t*)alloc(320000);
  P.Apk1 = (f16_t*)alloc(320000);
  P.Apk2 = (f16_t*)alloc(320000);
  P.Zg = alloc((size_t)ROWS_ * 384);
  P.U = alloc((size_t)ROWS_ * 64);
  P.h0 = alloc((size_t)ROWS_ * 64);
  P.h1 = alloc((size_t)ROWS_ * 64);
  P.txe = alloc((size_t)768 * 1600);
  P.tye = alloc((size_t)768 * 1600);
  P.hidb = alloc(15360);
  P.partial = alloc(8192);
  const int kpnc[8] = {224 * 128, 224 * 64, 384 * 128, 384 * 64, 224 * 128, 224 * 64, 384 * 128, 384 * 64};
  for (int w = 0; w < 8; ++w) {
    P.wh[w] = (f16_t*)alloc((kpnc[w] + 1) / 2);
    P.wl[w] = (f16_t*)alloc((kpnc[w] + 1) / 2);
  }

  k_p0<<<512, 256, 0, stream>>>(P);
  k_p1<<<512, 256, 0, stream>>>(P);
  k_p2<<<512, 256, 0, stream>>>(P);

  auto cell0 = [&](int mode, int dec, int t) {
    g_graph<0><<<2 * 7 * 64, 256, 0, stream>>>(P, mode, t, 68, 0);
    g_gate<0><<<800, 256, 0, stream>>>(P, dec);
    g_graph<0><<<1 * 7 * 64, 256, 0, stream>>>(P, 3, t, 64, 4);
    g_cand<0><<<400, 256, 0, stream>>>(P, dec);
  };
  auto cell1 = [&](int dec, int t) {
    g_graph<1><<<2 * 7 * 64, 256, 0, stream>>>(P, 2, t, 128, 0);
    g_gate<1><<<800, 256, 0, stream>>>(P, dec);
    g_graph<1><<<1 * 7 * 64, 256, 0, stream>>>(P, 3, t, 64, 64);
    g_cand<1><<<400, 256, 0, stream>>>(P, dec);
  };

  for (int t = 0; t < 12; ++t) {
    cell0(0, 0, t);
    cell1(0, t);
  }
  for (int t = 0; t < 12; ++t) {
    cell0(1, 1, t);
    cell1(1, t);
    k_m1<<<256, 256, 0, stream>>>(P);
    k_m2<<<200, 256, 0, stream>>>(P, t);
  }
}